// Round 3
// baseline (215.289 us; speedup 1.0000x reference)
//
#include <hip/hip_runtime.h>
#include <hip/hip_bf16.h>

// Problem constants (fixed by the reference).
#define BB 32
#define SS 256
#define DD 256
#define UU 256
#define LL 16
#define DEG 16
#define NN (BB * SS)   // 8192 nodes
#define EE (NN * DEG)  // 131072 edges per branch
#define NSLICE 33      // slice 0 = self-loop, 1..16 = in labels, 17..32 = out labels
#define KMAIN (NSLICE * DD)   // 8448
#define KEXT 256              // ext cols: wsum/bias GEMM trick (33 used, rest 0)
#define KTOT (KMAIN + KEXT)   // 8704 = 34*256
#define KSPLIT 8
#define KS (KTOT / KSPLIT)    // 1088 = 17*64
#define TM 256                // rows (nodes) per block
#define BK 64                 // k step
#define NT (KS / BK)          // 17 k-tiles per block

using short8 = __attribute__((ext_vector_type(8))) short;  // 8 bf16 (4 VGPRs)
using f32x4  = __attribute__((ext_vector_type(4))) float;  // MFMA accumulator

// async global->LDS, 16B per lane, LDS dest = wave-uniform base + lane*16
#define GLDS(g, l)                                                        \
  __builtin_amdgcn_global_load_lds(                                       \
      (const __attribute__((address_space(1))) void*)(g),                 \
      (__attribute__((address_space(3))) void*)(l), 16, 0, 0)

__device__ __forceinline__ float bf2f(unsigned short v) {
  union { unsigned u; float f; } t;
  t.u = ((unsigned)v) << 16;
  return t.f;
}
__device__ __forceinline__ unsigned short f2bf(float f) {
  __hip_bfloat16 h = __float2bfloat16(f);
  return *(unsigned short*)&h;
}
__device__ __forceinline__ float sigm(float x) {
  return 1.f / (1.f + __expf(-x));
}

// ---------------------------------------------------------------------------
// K1: blocks [0,NN): x cast to bf16 + 3 gate dots.
// blocks [NN, NN+(NSLICE+1)*64): weight transpose Vt[u][z*256+d] = V_z[d][u]
// plus ext bias rows Vt[u][KMAIN+j] = bias_all[j][u]. (round-0 proven)
// ---------------------------------------------------------------------------
__global__ __launch_bounds__(256) void k_pre(
    const float* __restrict__ src, const float* __restrict__ gin,
    const float* __restrict__ gout, const float* __restrict__ gloop,
    const float* __restrict__ Vin, const float* __restrict__ Vout,
    const float* __restrict__ Wself, const float* __restrict__ b_in,
    const float* __restrict__ b_out,
    __hip_bfloat16* __restrict__ x_bf, float* __restrict__ xg_in,
    float* __restrict__ xg_out, float* __restrict__ xg_loop,
    __hip_bfloat16* __restrict__ Vt) {
  int bid = blockIdx.x;
  if (bid < NN) {
    int n = bid;
    int b = n / SS, s = n % SS;
    int d = threadIdx.x;
    float v = src[(size_t)(s * BB + b) * DD + d];
    x_bf[(size_t)n * DD + d] = __float2bfloat16(v);
    float p0 = v * gin[d], p1 = v * gout[d], p2 = v * gloop[d];
#pragma unroll
    for (int o = 32; o > 0; o >>= 1) {
      p0 += __shfl_down(p0, o);
      p1 += __shfl_down(p1, o);
      p2 += __shfl_down(p2, o);
    }
    __shared__ float r0[4], r1[4], r2[4];
    int w = threadIdx.x >> 6, lane = threadIdx.x & 63;
    if (lane == 0) { r0[w] = p0; r1[w] = p1; r2[w] = p2; }
    __syncthreads();
    if (threadIdx.x == 0) {
      xg_in[n]   = r0[0] + r0[1] + r0[2] + r0[3];
      xg_out[n]  = r1[0] + r1[1] + r1[2] + r1[3];
      xg_loop[n] = r2[0] + r2[1] + r2[2] + r2[3];
    }
    return;
  }
  int t = bid - NN;
  int z = t >> 6;                 // 0..NSLICE
  int rem = t & 63;
  int bx = rem & 7, by = rem >> 3;
  int tid = threadIdx.x;
  int tx = tid & 31, ty = tid >> 5;
  if (z == NSLICE) {              // ext bias rows
    int u0 = bx * 32, j0 = by * 32;
#pragma unroll
    for (int i = 0; i < 4; i++) {
      int u = u0 + ty + i * 8, j = j0 + tx;
      float v = 0.f;
      if (j >= 1 && j <= LL)         v = b_in[(j - 1) * UU + u];
      else if (j > LL && j < NSLICE) v = b_out[(j - 1 - LL) * UU + u];
      Vt[(size_t)u * KTOT + KMAIN + j] = __float2bfloat16(v);
    }
    return;
  }
  __shared__ float tbuf[32][33];
  const float* srcM = (z == 0) ? Wself
                    : (z <= LL ? Vin  + (size_t)(z - 1)      * DD * UU
                               : Vout + (size_t)(z - 1 - LL) * DD * UU);
  int u0 = bx * 32, d0 = by * 32;
#pragma unroll
  for (int i = 0; i < 4; i++) {
    int dr = ty + i * 8;
    tbuf[dr][tx] = srcM[(size_t)(d0 + dr) * UU + u0 + tx];
  }
  __syncthreads();
#pragma unroll
  for (int i = 0; i < 4; i++) {
    int ur = ty + i * 8;
    Vt[(size_t)(u0 + ur) * KTOT + z * DD + d0 + tx] = __float2bfloat16(tbuf[tx][ur]);
  }
}

// ---------------------------------------------------------------------------
// K2: per-node edge lists sorted by slice (CSR). One block per node.
// es_src/es_w sorted by slice; e_start[n][z] = #edges with slice < z (z<=33);
// wl[n] = sigm(xg_loop)*mask_loop.
// ---------------------------------------------------------------------------
__global__ __launch_bounds__(64) void k_edges(
    const float* __restrict__ xg_in, const float* __restrict__ xg_out,
    const float* __restrict__ xg_loop,
    const float* __restrict__ b_ing, const float* __restrict__ b_outg,
    const int* __restrict__ arc_in, const int* __restrict__ arc_out,
    const int* __restrict__ lab_in, const int* __restrict__ lab_out,
    const float* __restrict__ mask_in, const float* __restrict__ mask_out,
    const float* __restrict__ mask_loop,
    int* __restrict__ es_src, float* __restrict__ es_w,
    unsigned char* __restrict__ e_start, float* __restrict__ wl) {
  __shared__ int u_sl[32], u_src[32];
  __shared__ float u_w[32];
  int n = blockIdx.x, tid = threadIdx.x;
  if (tid < 32) {
    int br = tid >> 4, k = tid & 15;
    int e = n * DEG + k;
    const int* a = br ? arc_out : arc_in;
    int l = (br ? lab_out : lab_in)[e];
    int srcn = a[e] * SS + a[EE + e];
    float g = (br ? xg_out : xg_in)[srcn] + (br ? b_outg : b_ing)[l];
    u_sl[tid] = 1 + br * LL + l;
    u_src[tid] = srcn;
    u_w[tid] = sigm(g) * (br ? mask_out : mask_in)[e];
  }
  __syncthreads();
  if (tid < 32) {
    int my = u_sl[tid];
    int rank = 0;
#pragma unroll
    for (int j = 0; j < 32; j++) {
      int oj = u_sl[j];
      rank += (oj < my || (oj == my && j < tid)) ? 1 : 0;
    }
    es_src[(size_t)n * 32 + rank] = u_src[tid];
    es_w[(size_t)n * 32 + rank] = u_w[tid];
  }
  if (tid < 34) {
    int cnt = 0;
#pragma unroll
    for (int j = 0; j < 32; j++) cnt += (u_sl[j] < tid) ? 1 : 0;
    e_start[(size_t)n * 34 + tid] = (unsigned char)cnt;
  }
  if (tid == 0) wl[n] = sigm(xg_loop[n]) * mask_loop[n];
}

// ---------------------------------------------------------------------------
// K3 (k_fused): GEMM with ON-THE-FLY A-tile gather. Never materializes Y.
// A[n][k] for k-tile (slice z, d-chunk) = sum over node n's slice-z edges of
// w_e * x[src_e][d-chunk] (slice 0 = wl*x[n]; ext tiles = wsum cols).
// x is 4 MB -> gathers hit L2/LLC, not HBM. B = Vt via global_load_lds
// (pre-swizzled source); A via swizzled ds_write_b128 (both sides swizzled,
// matching RD_* pattern). 2-phase double buffer, one __syncthreads per tile;
// gather loads for t+1 issued BEFORE tile t's MFMA (T14), consumed after.
// 512 thr = 8 waves (2x4); grid (NN/TM=32, KSPLIT=8) = 256 blocks = 1/CU.
// Epilogue: swapped-operand layout -> coalesced ushort4 stores (round-2
// proven) into bf16 partial[ksplit][NN][UU].
// ---------------------------------------------------------------------------
__global__ __launch_bounds__(512, 2) void k_fused(
    const __hip_bfloat16* __restrict__ X, const __hip_bfloat16* __restrict__ Vt,
    const int* __restrict__ es_src, const float* __restrict__ es_w,
    const unsigned char* __restrict__ e_start, const float* __restrict__ wl,
    __hip_bfloat16* __restrict__ partial) {
  __shared__ __align__(16) __hip_bfloat16 As[2][TM * BK];
  __shared__ __align__(16) __hip_bfloat16 Bs[2][TM * BK];

  const int tid = threadIdx.x;
  const int w = tid >> 6, lane = tid & 63;
  const int wm = w >> 2, wn = w & 3;           // wave grid 2x4
  const int lrow = lane & 15, quad = lane >> 4;
  const int row0 = blockIdx.x * TM;
  const int kbeg = blockIdx.y * KS;

  // gather mapping: thread owns node n_loc, 32-d half
  const int n_loc = tid >> 1, half = tid & 1, d0l = half * 32;
  const int n = row0 + n_loc;
  const float wlv = wl[n];
  const unsigned short* xp = (const unsigned short*)X;
  const unsigned char* esp = e_start + (size_t)n * 34;
  const int* srcp = es_src + (size_t)n * 32;
  const float* wp = es_w + (size_t)n * 32;

  // B staging (global_load_lds, pre-swizzled source)
  const int arow = tid >> 3;
  const int scol = ((tid & 7) ^ (arow & 7)) << 3;
  const __hip_bfloat16* srcB = Vt + (size_t)arow * KTOT + scol;

  // ds_read swizzled k-slot offsets for the two k-halves
  const int sc0 = ((quad ^ (lrow & 7)) << 3);
  const int sc1 = (((4 + quad) ^ (lrow & 7)) << 3);

#define STG_B(bufi, k0)                                                    \
  {                                                                        \
    _Pragma("unroll")                                                      \
    for (int r = 0; r < 4; ++r)                                            \
      GLDS(srcB + (size_t)(r * 64) * KTOT + (k0),                          \
           &Bs[bufi][r * 4096 + (w << 9)]);                                \
  }

  // ---- A-tile gather: ISSUE (loads for up to 2 edges) / FINISH ----
  int zB, nE, eSt, kgB;
  float stw[2];
  short8 stg[2][4];

#define ISSUE(kg)                                                          \
  {                                                                        \
    kgB = (kg);                                                            \
    zB = kgB >> 8;                                                         \
    int dB = (kgB & 255) + d0l;                                            \
    nE = 0; eSt = 0;                                                       \
    if (zB == 0) {                                                         \
      nE = 1; stw[0] = wlv;                                                \
      const short8* xs = (const short8*)&xp[(size_t)n * DD + dB];          \
      _Pragma("unroll")                                                    \
      for (int c = 0; c < 4; ++c) stg[0][c] = xs[c];                       \
    } else if (zB < NSLICE) {                                              \
      eSt = esp[zB];                                                       \
      nE = (int)esp[zB + 1] - eSt;                                         \
      if (nE >= 1) {                                                       \
        stw[0] = wp[eSt];                                                  \
        const short8* xs =                                                 \
            (const short8*)&xp[(size_t)srcp[eSt] * DD + dB];               \
        _Pragma("unroll")                                                  \
        for (int c = 0; c < 4; ++c) stg[0][c] = xs[c];                     \
      }                                                                    \
      if (nE >= 2) {                                                       \
        stw[1] = wp[eSt + 1];                                              \
        const short8* xs =                                                 \
            (const short8*)&xp[(size_t)srcp[eSt + 1] * DD + dB];           \
        _Pragma("unroll")                                                  \
        for (int c = 0; c < 4; ++c) stg[1][c] = xs[c];                     \
      }                                                                    \
    }                                                                      \
  }

#define FINISH(bufi)                                                       \
  {                                                                        \
    float a[32];                                                           \
    _Pragma("unroll")                                                      \
    for (int c = 0; c < 32; ++c) a[c] = 0.f;                               \
    int dB = (kgB & 255) + d0l;                                            \
    if (zB >= NSLICE) {          /* ext tile: wsum columns */              \
      int jb = kgB + d0l - KMAIN;                                          \
      _Pragma("unroll")                                                    \
      for (int c = 0; c < 32; ++c) {                                       \
        int j = jb + c;                                                    \
        float s = 0.f;                                                     \
        if (j >= 1 && j < NSLICE) {                                        \
          int st = esp[j], en = esp[j + 1];                                \
          for (int i = st; i < en; ++i) s += wp[i];                        \
        }                                                                  \
        a[c] = s;                                                          \
      }                                                                    \
    } else {                                                               \
      if (nE >= 1) {                                                       \
        float ww = stw[0];                                                 \
        _Pragma("unroll")                                                  \
        for (int c = 0; c < 4; ++c)                                        \
          _Pragma("unroll")                                                \
          for (int e = 0; e < 8; ++e)                                      \
            a[c * 8 + e] += ww * bf2f((unsigned short)stg[0][c][e]);       \
      }                                                                    \
      if (nE >= 2) {                                                       \
        float ww = stw[1];                                                 \
        _Pragma("unroll")                                                  \
        for (int c = 0; c < 4; ++c)                                        \
          _Pragma("unroll")                                                \
          for (int e = 0; e < 8; ++e)                                      \
            a[c * 8 + e] += ww * bf2f((unsigned short)stg[1][c][e]);       \
      }                                                                    \
      for (int i = 2; i < nE; ++i) {   /* rare: >2 same-slice edges */     \
        float ww = wp[eSt + i];                                            \
        const short8* xs =                                                 \
            (const short8*)&xp[(size_t)srcp[eSt + i] * DD + dB];           \
        _Pragma("unroll")                                                  \
        for (int c = 0; c < 4; ++c) {                                      \
          short8 v = xs[c];                                                \
          _Pragma("unroll")                                                \
          for (int e = 0; e < 8; ++e)                                      \
            a[c * 8 + e] += ww * bf2f((unsigned short)v[e]);               \
        }                                                                  \
      }                                                                    \
    }                                                                      \
    _Pragma("unroll")                                                      \
    for (int c = 0; c < 4; ++c) {                                          \
      short8 p;                                                            \
      _Pragma("unroll")                                                    \
      for (int e = 0; e < 8; ++e) p[e] = (short)f2bf(a[c * 8 + e]);        \
      int slot = (half * 4 + c) ^ (n_loc & 7);                             \
      *(short8*)&As[bufi][n_loc * 64 + slot * 8] = p;                      \
    }                                                                      \
  }

#define RD_A(DST, IBASE)                                                   \
  _Pragma("unroll")                                                        \
  for (int i = 0; i < 4; ++i) {                                            \
    int ro = (wm * 128 + ((IBASE) + i) * 16 + lrow) * BK;                  \
    DST[i][0] = *(const short8*)&as[ro + sc0];                             \
    DST[i][1] = *(const short8*)&as[ro + sc1];                             \
  }
#define RD_B(DST, JBASE)                                                   \
  _Pragma("unroll")                                                        \
  for (int j = 0; j < 2; ++j) {                                            \
    int ro = (wn * 64 + ((JBASE) + j) * 16 + lrow) * BK;                   \
    DST[j][0] = *(const short8*)&bs[ro + sc0];                             \
    DST[j][1] = *(const short8*)&bs[ro + sc1];                             \
  }
// swapped operands: D = B_frag x A_frag (C^T fragments, round-2 proven)
#define MFMA16(AF, BF, IOFF, JOFF)                                         \
  {                                                                        \
    _Pragma("unroll")                                                      \
    for (int i = 0; i < 4; ++i)                                            \
      _Pragma("unroll")                                                    \
      for (int j = 0; j < 2; ++j) {                                        \
        acc[(IOFF) + i][(JOFF) + j] =                                      \
            __builtin_amdgcn_mfma_f32_16x16x32_bf16(                       \
                BF[j][0], AF[i][0], acc[(IOFF) + i][(JOFF) + j], 0, 0, 0); \
        acc[(IOFF) + i][(JOFF) + j] =                                      \
            __builtin_amdgcn_mfma_f32_16x16x32_bf16(                       \
                BF[j][1], AF[i][1], acc[(IOFF) + i][(JOFF) + j], 0, 0, 0); \
      }                                                                    \
  }
#define MFMA_TILE(bufi)                                                    \
  {                                                                        \
    const __hip_bfloat16* as = &As[bufi][0];                               \
    const __hip_bfloat16* bs = &Bs[bufi][0];                               \
    short8 afA[4][2], afB[4][2], bfA[2][2], bfB[2][2];                     \
    RD_A(afA, 0);                                                          \
    RD_B(bfA, 0);                                                          \
    MFMA16(afA, bfA, 0, 0);                                                \
    RD_B(bfB, 2);                                                          \
    MFMA16(afA, bfB, 0, 2);                                                \
    RD_A(afB, 4);                                                          \
    MFMA16(afB, bfA, 4, 0);                                                \
    MFMA16(afB, bfB, 4, 2);                                                \
  }

  f32x4 acc[8][4] = {};

  // Prologue: build tile 0 (A inline, B async); barrier drains both.
  STG_B(0, kbeg);
  ISSUE(kbeg);
  FINISH(0);
  __syncthreads();

  for (int t = 0; t < NT; ++t) {
    const int cur = t & 1;
    if (t + 1 < NT) {
      STG_B(cur ^ 1, kbeg + (t + 1) * BK);   // async B for next tile
      ISSUE(kbeg + (t + 1) * BK);            // gather loads for next A-tile
    }
    MFMA_TILE(cur);                          // compute on current tile
    if (t + 1 < NT) FINISH(cur ^ 1);         // consume gathers, write next A
    __syncthreads();                         // drains GLDS + orders buffers
  }
#undef STG_B
#undef ISSUE
#undef FINISH
#undef RD_A
#undef RD_B
#undef MFMA16
#undef MFMA_TILE

  // Swapped C/D layout: lane owns row n = ...+lrow, u = j*16 + quad*4..+3
  __hip_bfloat16* P = partial + (size_t)blockIdx.y * NN * UU;
  unsigned short* Pp = (unsigned short*)P;
#pragma unroll
  for (int i = 0; i < 8; ++i)
#pragma unroll
    for (int j = 0; j < 4; ++j) {
      int nr = row0 + wm * 128 + i * 16 + lrow;
      int u0 = wn * 64 + j * 16 + quad * 4;
      ushort4 o;
      o.x = f2bf(acc[i][j][0]); o.y = f2bf(acc[i][j][1]);
      o.z = f2bf(acc[i][j][2]); o.w = f2bf(acc[i][j][3]);
      *(ushort4*)&Pp[(size_t)nr * UU + u0] = o;
    }
}

// ---------------------------------------------------------------------------
// K4: reduce KSPLIT bf16 partials + relu + sent_mask + transpose (round-0).
// ---------------------------------------------------------------------------
__global__ __launch_bounds__(64) void k_finish(
    const __hip_bfloat16* __restrict__ partial, const float* __restrict__ sent,
    float* __restrict__ out) {
  int n = blockIdx.x, u4 = threadIdx.x * 4;
  size_t idx = (size_t)n * UU + u4;
  const unsigned short* pp = (const unsigned short*)partial;
  float a0 = 0.f, a1 = 0.f, a2 = 0.f, a3 = 0.f;
#pragma unroll
  for (int z = 0; z < KSPLIT; z++) {
    ushort4 v = *(const ushort4*)&pp[(size_t)z * NN * UU + idx];
    a0 += bf2f(v.x); a1 += bf2f(v.y); a2 += bf2f(v.z); a3 += bf2f(v.w);
  }
  int s = n % SS, b = n / SS;
  float sm = sent[s * BB + b];
  float4 o;
  o.x = fmaxf(a0, 0.f) * sm; o.y = fmaxf(a1, 0.f) * sm;
  o.z = fmaxf(a2, 0.f) * sm; o.w = fmaxf(a3, 0.f) * sm;
  *(float4*)&out[((size_t)s * BB + b) * UU + u4] = o;
}

extern "C" void kernel_launch(void* const* d_in, const int* in_sizes, int n_in,
                              void* d_out, int out_size, void* d_ws, size_t ws_size,
                              hipStream_t stream) {
  const float* src      = (const float*)d_in[0];
  const float* V_in     = (const float*)d_in[1];
  const float* b_in     = (const float*)d_in[2];
  const float* V_ing    = (const float*)d_in[3];
  const float* b_ing    = (const float*)d_in[4];
  const float* V_out    = (const float*)d_in[5];
  const float* b_out    = (const float*)d_in[6];
  const float* V_outg   = (const float*)d_in[7];
  const float* b_outg   = (const float*)d_in[8];
  const float* W_self   = (const float*)d_in[9];
  const float* W_selfg  = (const float*)d_in[10];
  const int* arc_in     = (const int*)d_in[11];
  const int* arc_out    = (const int*)d_in[12];
  const int* lab_in     = (const int*)d_in[13];
  const int* lab_out    = (const int*)d_in[14];
  const float* mask_in  = (const float*)d_in[15];
  const float* mask_out = (const float*)d_in[16];
  const float* mask_loop= (const float*)d_in[17];
  const float* sent     = (const float*)d_in[18];
  float* out = (float*)d_out;

  char* ws = (char*)d_ws;
  size_t off = 0;
  auto alloc = [&](size_t bytes) -> void* {
    void* p = ws + off;
    off += (bytes + 255) & ~(size_t)255;
    return p;
  };
  __hip_bfloat16* x_bf = (__hip_bfloat16*)alloc((size_t)NN * DD * 2);       // 4 MB
  __hip_bfloat16* Vt   = (__hip_bfloat16*)alloc((size_t)UU * KTOT * 2);     // 4.5 MB
  float* xg_in   = (float*)alloc(NN * 4);
  float* xg_out  = (float*)alloc(NN * 4);
  float* xg_loop = (float*)alloc(NN * 4);
  int*   es_src  = (int*)alloc((size_t)NN * 32 * 4);                        // 1 MB
  float* es_w    = (float*)alloc((size_t)NN * 32 * 4);                      // 1 MB
  unsigned char* e_start = (unsigned char*)alloc((size_t)NN * 34);          // 0.3 MB
  float* wl      = (float*)alloc((size_t)NN * 4);
  __hip_bfloat16* partial =
      (__hip_bfloat16*)alloc((size_t)KSPLIT * NN * UU * 2);                 // 34 MB

  k_pre<<<NN + (NSLICE + 1) * 64, 256, 0, stream>>>(
      src, V_ing, V_outg, W_selfg, V_in, V_out, W_self, b_in, b_out,
      x_bf, xg_in, xg_out, xg_loop, Vt);
  k_edges<<<NN, 64, 0, stream>>>(xg_in, xg_out, xg_loop, b_ing, b_outg,
                                 arc_in, arc_out, lab_in, lab_out,
                                 mask_in, mask_out, mask_loop,
                                 es_src, es_w, e_start, wl);
  k_fused<<<dim3(NN / TM, KSPLIT), 512, 0, stream>>>(
      x_bf, Vt, es_src, es_w, e_start, wl, partial);
  k_finish<<<NN, 64, 0, stream>>>(partial, sent, out);
}